// Round 6
// baseline (949.677 us; speedup 1.0000x reference)
//
#include <hip/hip_runtime.h>

using bf16x8 = __attribute__((ext_vector_type(8))) short;
using short8 = __attribute__((ext_vector_type(8))) short;
using f32x4  = __attribute__((ext_vector_type(4))) float;
using u32x4  = __attribute__((ext_vector_type(4))) unsigned;

#define T_SEQ 512
#define MFMA(A, B, C) __builtin_amdgcn_mfma_f32_16x16x32_bf16((A), (B), (C), 0, 0, 0)
#define FENCE() __builtin_amdgcn_sched_barrier(0)

static constexpr float NL2E  = -1.44269504f;   // -log2(e)
static constexpr float N2L2E = -2.88539008f;   // -2*log2(e)

// Truncation split: hi = bf16-truncate(v), lo = bf16-truncate(v - hi) (residual exact).
__device__ __forceinline__ void split8_tr(f32x4 a, f32x4 b, bf16x8& hi, bf16x8& lo) {
    u32x4 ua = __builtin_bit_cast(u32x4, a);
    u32x4 ub = __builtin_bit_cast(u32x4, b);
    u32x4 m  = {0xffff0000u, 0xffff0000u, 0xffff0000u, 0xffff0000u};
    f32x4 ra = a - __builtin_bit_cast(f32x4, ua & m);
    f32x4 rb = b - __builtin_bit_cast(f32x4, ub & m);
    short8 sa  = __builtin_bit_cast(short8, a);
    short8 sb  = __builtin_bit_cast(short8, b);
    short8 sra = __builtin_bit_cast(short8, ra);
    short8 srb = __builtin_bit_cast(short8, rb);
    hi = __builtin_shufflevector(sa, sb, 1, 3, 5, 7, 9, 11, 13, 15);
    lo = __builtin_shufflevector(sra, srb, 1, 3, 5, 7, 9, 11, 13, 15);
}

__device__ __forceinline__ void pack_frag_tr(const float (&hf)[8], bf16x8& hi, bf16x8& lo) {
    f32x4 a = {hf[0], hf[1], hf[2], hf[3]};
    f32x4 b = {hf[4], hf[5], hf[6], hf[7]};
    split8_tr(a, b, hi, lo);
}

// Scalar gates for prologue/epilogue only (rarely executed).
__device__ __forceinline__ float sigmf(float v) {
    return __builtin_amdgcn_rcpf(1.f + __builtin_amdgcn_exp2f(v * NL2E));
}
__device__ __forceinline__ float tanhf_(float v) {
    float e = __builtin_amdgcn_exp2f(fminf(v * N2L2E, 126.f));
    float q = __builtin_amdgcn_rcpf(1.f + e);
    return fmaf(e * q, -2.f, 1.f);
}
__device__ __forceinline__ void gate8(const f32x4 (&a)[8], float (&hf)[8]) {
    #pragma unroll
    for (int s = 0; s < 2; ++s) {
        #pragma unroll
        for (int j = 0; j < 4; ++j) {
            float r = sigmf(a[s][j]);
            float z = sigmf(a[2 + s][j]);
            float nn = tanhf_(fmaf(r, a[6 + s][j], a[4 + s][j]));
            float& h = hf[4 * s + j];
            h = nn + z * (h - nn);
        }
    }
}

// One wave = 16 batches. D = W(96x32)*in(32x16b). Per-lane: batch = b0+(lane&15),
// q = lane>>4; frag elements 0..3 = units 4q+j, 4..7 = units 16+4q+j (same map for
// A and B frags -> correct under any k-slot convention). D: col=lane&15, row=4q+reg.
__global__ __launch_bounds__(64, 1)
void gru2_mfma(const float* __restrict__ x,
               const float* __restrict__ W_ih0, const float* __restrict__ W_hh0,
               const float* __restrict__ b_ih0, const float* __restrict__ b_hh0,
               const float* __restrict__ W_ih1, const float* __restrict__ W_hh1,
               const float* __restrict__ b_ih1, const float* __restrict__ b_hh1,
               const float* __restrict__ W_proj, const float* __restrict__ b_proj,
               float* __restrict__ out)
{
    const int lane = threadIdx.x;
    const int r16  = lane & 15;
    const int q    = lane >> 4;
    const int b0   = blockIdx.x * 16;

    // ---- weight fragments (hi/lo truncation split) ----
    // Destined for AGPRs: arch-VGPR cap is 256 on gfx950; the unified file's
    // AGPR half holds MFMA A/B/C operands directly, so weights+rz-biases live
    // there (224 AGPRs) and the VGPR half keeps acc/gates/state (~220).
    bf16x8 Wh[4][6], Wl[4][6];
    {
        const float* Ws[4] = {W_ih0, W_hh0, W_ih1, W_hh1};
        #pragma unroll
        for (int m = 0; m < 4; ++m) {
            #pragma unroll
            for (int t = 0; t < 6; ++t) {
                const float* p = Ws[m] + (16 * t + r16) * 32 + 4 * q;
                split8_tr(*(const f32x4*)p, *(const f32x4*)(p + 16), Wh[m][t], Wl[m][t]);
            }
        }
    }

    // ---- bias fragments (acc layout: element reg -> row 16t+4q+reg) ----
    f32x4 brz0[4], brz1[4], bxn0[2], bhn0[2], bxn1[2], bhn1[2];
    #pragma unroll
    for (int t = 0; t < 4; ++t) {
        brz0[t] = *(const f32x4*)(b_ih0 + 16 * t + 4 * q) + *(const f32x4*)(b_hh0 + 16 * t + 4 * q);
        brz1[t] = *(const f32x4*)(b_ih1 + 16 * t + 4 * q) + *(const f32x4*)(b_hh1 + 16 * t + 4 * q);
    }
    #pragma unroll
    for (int t = 0; t < 2; ++t) {
        bxn0[t] = *(const f32x4*)(b_ih0 + 64 + 16 * t + 4 * q);
        bhn0[t] = *(const f32x4*)(b_hh0 + 64 + 16 * t + 4 * q);
        bxn1[t] = *(const f32x4*)(b_ih1 + 64 + 16 * t + 4 * q);
        bhn1[t] = *(const f32x4*)(b_hh1 + 64 + 16 * t + 4 * q);
    }

    // Establish AGPR placement before the loop.
    #pragma unroll
    for (int m = 0; m < 4; ++m)
        #pragma unroll
        for (int t = 0; t < 6; ++t)
            asm volatile("" : "+a"(Wh[m][t]), "+a"(Wl[m][t]));
    #pragma unroll
    for (int t = 0; t < 4; ++t) asm volatile("" : "+a"(brz0[t]), "+a"(brz1[t]));

    // ---- state ----
    bf16x8 H0h = {}, H0l = {}, H1h = {}, H1l = {};
    float h0f[8] = {}, h1f[8] = {};

    const float* xp = x + (size_t)(b0 + r16) * (T_SEQ * 32) + 4 * q;
    f32x4 xA = *(const f32x4*)(xp);
    f32x4 xB = *(const f32x4*)(xp + 16);

    // ---- prologue: L0 step t=0 (h0[-1] = 0) ----
    {
        bf16x8 xh, xl;
        split8_tr(xA, xB, xh, xl);
        xA = *(const f32x4*)(xp + 32);
        xB = *(const f32x4*)(xp + 48);
        f32x4 a[8];
        #pragma unroll
        for (int tt = 0; tt < 4; ++tt) {
            f32x4 c = MFMA(Wh[0][tt], xh, brz0[tt]);
            c = MFMA(Wh[0][tt], xl, c);
            a[tt] = MFMA(Wl[0][tt], xh, c);
        }
        #pragma unroll
        for (int s = 0; s < 2; ++s) {
            f32x4 c = MFMA(Wh[0][4 + s], xh, bxn0[s]);
            c = MFMA(Wh[0][4 + s], xl, c);
            a[4 + s] = MFMA(Wl[0][4 + s], xh, c);
            a[6 + s] = bhn0[s];
        }
        gate8(a, h0f);
        pack_frag_tr(h0f, H0h, H0l);
    }

    // ---- main loop: L1 computes h1[t-1], L0 computes h0[t]; all 72 MFMAs
    // issuable at step start, round-robin across 16 chains. In-loop "+a"/"+v"
    // pins are loop-carried opaque defs: the allocator cannot remat the weight
    // loads, forcing true AGPR residency across the backedge.
    #pragma unroll 1
    for (int t = 1; t < T_SEQ; ++t) {
        #pragma unroll
        for (int m = 0; m < 4; ++m)
            #pragma unroll
            for (int tt = 0; tt < 6; ++tt)
                asm volatile("" : "+a"(Wh[m][tt]), "+a"(Wl[m][tt]));
        #pragma unroll
        for (int tt = 0; tt < 4; ++tt) asm volatile("" : "+a"(brz0[tt]), "+a"(brz1[tt]));
        #pragma unroll
        for (int tt = 0; tt < 2; ++tt)
            asm volatile("" : "+v"(bxn0[tt]), "+v"(bhn0[tt]), "+v"(bxn1[tt]), "+v"(bhn1[tt]));

        bf16x8 xh, xl;
        split8_tr(xA, xB, xh, xl);               // x[t]
        const float* nx = xp + (size_t)((t + 1 < T_SEQ) ? t + 1 : t) * 32;
        f32x4 nA = *(const f32x4*)(nx);          // prefetch x[t+1]
        f32x4 nB = *(const f32x4*)(nx + 16);

        f32x4 acc[16];
        // chains: 0-3 L0 rz | 4-5 L0 xn | 6-7 L0 hn | 8-11 L1 rz | 12-13 L1 xn | 14-15 L1 hn
        // round 0: hi-W x hi-in (C = bias)
        #pragma unroll
        for (int tt = 0; tt < 4; ++tt) {
            acc[tt]     = MFMA(Wh[0][tt], xh,  brz0[tt]);
            acc[8 + tt] = MFMA(Wh[2][tt], H0h, brz1[tt]);
        }
        #pragma unroll
        for (int s = 0; s < 2; ++s) {
            acc[4 + s]  = MFMA(Wh[0][4 + s], xh,  bxn0[s]);
            acc[6 + s]  = MFMA(Wh[1][4 + s], H0h, bhn0[s]);
            acc[12 + s] = MFMA(Wh[2][4 + s], H0h, bxn1[s]);
            acc[14 + s] = MFMA(Wh[3][4 + s], H1h, bhn1[s]);
        }
        FENCE();
        // round 1: hi-W x lo-in
        #pragma unroll
        for (int tt = 0; tt < 4; ++tt) {
            acc[tt]     = MFMA(Wh[0][tt], xl,  acc[tt]);
            acc[8 + tt] = MFMA(Wh[2][tt], H0l, acc[8 + tt]);
        }
        #pragma unroll
        for (int s = 0; s < 2; ++s) {
            acc[4 + s]  = MFMA(Wh[0][4 + s], xl,  acc[4 + s]);
            acc[6 + s]  = MFMA(Wh[1][4 + s], H0l, acc[6 + s]);
            acc[12 + s] = MFMA(Wh[2][4 + s], H0l, acc[12 + s]);
            acc[14 + s] = MFMA(Wh[3][4 + s], H1l, acc[14 + s]);
        }
        FENCE();
        // round 2: lo-W x hi-in
        #pragma unroll
        for (int tt = 0; tt < 4; ++tt) {
            acc[tt]     = MFMA(Wl[0][tt], xh,  acc[tt]);
            acc[8 + tt] = MFMA(Wl[2][tt], H0h, acc[8 + tt]);
        }
        #pragma unroll
        for (int s = 0; s < 2; ++s) {
            acc[4 + s]  = MFMA(Wl[0][4 + s], xh,  acc[4 + s]);
            acc[6 + s]  = MFMA(Wl[1][4 + s], H0h, acc[6 + s]);
            acc[12 + s] = MFMA(Wl[2][4 + s], H0h, acc[12 + s]);
            acc[14 + s] = MFMA(Wl[3][4 + s], H1h, acc[14 + s]);
        }
        FENCE();
        // rounds 3-5: rz chains, state-side products
        #pragma unroll
        for (int tt = 0; tt < 4; ++tt) {
            acc[tt]     = MFMA(Wh[1][tt], H0h, acc[tt]);
            acc[8 + tt] = MFMA(Wh[3][tt], H1h, acc[8 + tt]);
        }
        FENCE();
        #pragma unroll
        for (int tt = 0; tt < 4; ++tt) {
            acc[tt]     = MFMA(Wh[1][tt], H0l, acc[tt]);
            acc[8 + tt] = MFMA(Wh[3][tt], H1l, acc[8 + tt]);
        }
        FENCE();
        #pragma unroll
        for (int tt = 0; tt < 4; ++tt) {
            acc[tt]     = MFMA(Wl[1][tt], H0h, acc[tt]);
            acc[8 + tt] = MFMA(Wl[3][tt], H1h, acc[8 + tt]);
        }
        FENCE();

        // ---- gates, level-major over 16 independent element chains ----
        float vr[16], vz[16], vax[16], vah[16], hOld[16];
        #pragma unroll
        for (int e = 0; e < 16; ++e) {
            const int L = e >> 3, s = (e >> 2) & 1, j = e & 3;
            vr[e]  = acc[8 * L + s][j];
            vz[e]  = acc[8 * L + 2 + s][j];
            vax[e] = acc[8 * L + 4 + s][j];
            vah[e] = acc[8 * L + 6 + s][j];
            hOld[e] = L ? h1f[e & 7] : h0f[e & 7];
        }
        float er[16], ez[16];
        #pragma unroll
        for (int e = 0; e < 16; ++e) er[e] = __builtin_amdgcn_exp2f(vr[e] * NL2E);
        #pragma unroll
        for (int e = 0; e < 16; ++e) ez[e] = __builtin_amdgcn_exp2f(vz[e] * NL2E);
        FENCE();
        float gr[16], gz[16];
        #pragma unroll
        for (int e = 0; e < 16; ++e) gr[e] = __builtin_amdgcn_rcpf(1.f + er[e]);
        #pragma unroll
        for (int e = 0; e < 16; ++e) gz[e] = __builtin_amdgcn_rcpf(1.f + ez[e]);
        FENCE();
        float en[16];
        #pragma unroll
        for (int e = 0; e < 16; ++e) {
            float u = fmaf(gr[e], vah[e], vax[e]);
            en[e] = __builtin_amdgcn_exp2f(fminf(u * N2L2E, 126.f));
        }
        FENCE();
        float qn[16];
        #pragma unroll
        for (int e = 0; e < 16; ++e) qn[e] = __builtin_amdgcn_rcpf(1.f + en[e]);
        FENCE();
        #pragma unroll
        for (int e = 0; e < 16; ++e) {
            float nn = fmaf(en[e] * qn[e], -2.f, 1.f);
            hOld[e] = fmaf(gz[e], hOld[e] - nn, nn);
        }
        #pragma unroll
        for (int e = 0; e < 8; ++e) { h0f[e] = hOld[e]; h1f[e] = hOld[8 + e]; }
        FENCE();
        pack_frag_tr(h0f, H0h, H0l);
        pack_frag_tr(h1f, H1h, H1l);
        xA = nA; xB = nB;
    }

    // ---- epilogue: L1 for final step (input = h0[511], state = h1[510]) ----
    {
        f32x4 a[8];
        #pragma unroll
        for (int tt = 0; tt < 4; ++tt) {
            f32x4 c = MFMA(Wh[2][tt], H0h, brz1[tt]);
            c = MFMA(Wh[2][tt], H0l, c);
            c = MFMA(Wl[2][tt], H0h, c);
            c = MFMA(Wh[3][tt], H1h, c);
            c = MFMA(Wh[3][tt], H1l, c);
            a[tt] = MFMA(Wl[3][tt], H1h, c);
        }
        #pragma unroll
        for (int s = 0; s < 2; ++s) {
            f32x4 c = MFMA(Wh[2][4 + s], H0h, bxn1[s]);
            c = MFMA(Wh[2][4 + s], H0l, c);
            a[4 + s] = MFMA(Wl[2][4 + s], H0h, c);
            f32x4 d = MFMA(Wh[3][4 + s], H1h, bhn1[s]);
            d = MFMA(Wh[3][4 + s], H1l, d);
            a[6 + s] = MFMA(Wl[3][4 + s], H1h, d);
        }
        gate8(a, h1f);
        pack_frag_tr(h1f, H1h, H1l);
    }

    // ---- projection: out[b][o] = b_proj[o] + sum_u W_proj[o][u] * h1[u] ----
    const float* pp = W_proj + r16 * 32 + 4 * q;
    bf16x8 Wph, Wpl;
    split8_tr(*(const f32x4*)pp, *(const f32x4*)(pp + 16), Wph, Wpl);
    f32x4 accp = *(const f32x4*)(b_proj + 4 * q);   // element reg -> output 4q+reg
    accp = MFMA(Wph, H1h, accp);
    accp = MFMA(Wph, H1l, accp);
    accp = MFMA(Wpl, H1h, accp);

    #pragma unroll
    for (int rg = 0; rg < 4; ++rg)
        out[(b0 + r16) * 16 + 4 * q + rg] = accp[rg];
}

extern "C" void kernel_launch(void* const* d_in, const int* in_sizes, int n_in,
                              void* d_out, int out_size, void* d_ws, size_t ws_size,
                              hipStream_t stream) {
    const float* x      = (const float*)d_in[0];
    const float* W_ih0  = (const float*)d_in[1];
    const float* W_hh0  = (const float*)d_in[2];
    const float* b_ih0  = (const float*)d_in[3];
    const float* b_hh0  = (const float*)d_in[4];
    const float* W_ih1  = (const float*)d_in[5];
    const float* W_hh1  = (const float*)d_in[6];
    const float* b_ih1  = (const float*)d_in[7];
    const float* b_hh1  = (const float*)d_in[8];
    const float* W_proj = (const float*)d_in[9];
    const float* b_proj = (const float*)d_in[10];
    float* out = (float*)d_out;

    const int nb   = in_sizes[0] / (T_SEQ * 32);   // 4096 batch elements
    const int grid = nb / 16;                      // 16 batches per 1-wave block

    hipLaunchKernelGGL(gru2_mfma, dim3(grid), dim3(64), 0, stream,
                       x, W_ih0, W_hh0, b_ih0, b_hh0,
                       W_ih1, W_hh1, b_ih1, b_hh1, W_proj, b_proj, out);
}

// Round 7
// 424.715 us; speedup vs baseline: 2.2360x; 2.2360x over previous
//
#include <hip/hip_runtime.h>

using bf16x8 = __attribute__((ext_vector_type(8))) short;
using short8 = __attribute__((ext_vector_type(8))) short;
using f32x4  = __attribute__((ext_vector_type(4))) float;
using u32x4  = __attribute__((ext_vector_type(4))) unsigned;

#define T_SEQ 512
#define MFMA(A, B, C) __builtin_amdgcn_mfma_f32_16x16x32_bf16((A), (B), (C), 0, 0, 0)
#define FENCE() __builtin_amdgcn_sched_barrier(0)

static constexpr float NL2E  = -1.44269504f;   // -log2(e)
static constexpr float N2L2E = -2.88539008f;   // -2*log2(e)

// Truncation split: hi = bf16-truncate(v), lo = bf16-truncate(v - hi) (residual exact).
__device__ __forceinline__ void split8_tr(f32x4 a, f32x4 b, bf16x8& hi, bf16x8& lo) {
    u32x4 ua = __builtin_bit_cast(u32x4, a);
    u32x4 ub = __builtin_bit_cast(u32x4, b);
    u32x4 m  = {0xffff0000u, 0xffff0000u, 0xffff0000u, 0xffff0000u};
    f32x4 ra = a - __builtin_bit_cast(f32x4, ua & m);
    f32x4 rb = b - __builtin_bit_cast(f32x4, ub & m);
    short8 sa  = __builtin_bit_cast(short8, a);
    short8 sb  = __builtin_bit_cast(short8, b);
    short8 sra = __builtin_bit_cast(short8, ra);
    short8 srb = __builtin_bit_cast(short8, rb);
    hi = __builtin_shufflevector(sa, sb, 1, 3, 5, 7, 9, 11, 13, 15);
    lo = __builtin_shufflevector(sra, srb, 1, 3, 5, 7, 9, 11, 13, 15);
}

__device__ __forceinline__ void pack_frag_tr(const float (&hf)[8], bf16x8& hi, bf16x8& lo) {
    f32x4 a = {hf[0], hf[1], hf[2], hf[3]};
    f32x4 b = {hf[4], hf[5], hf[6], hf[7]};
    split8_tr(a, b, hi, lo);
}

// One GRU layer step for 16 batches on one wave: 36 MFMAs over 8 independent
// accumulator chains (0-3 rz, 4-5 xn, 6-7 hn), then 8-wide level-major gates.
// State-side products are issued FIRST (register-local) so wave 1's ds_read of
// `in` (h0 from the other wave) completes under ~18 MFMAs of latency cover.
__device__ __forceinline__ void wave_step(
    const bf16x8 (&WxH)[6], const bf16x8 (&WxL)[6],
    const bf16x8 (&WhH)[6], const bf16x8 (&WhL)[6],
    const f32x4 (&brz)[4], const f32x4 (&bxn)[2], const f32x4 (&bhn)[2],
    bf16x8 inh, bf16x8 inl,
    bf16x8& Hh, bf16x8& Hl, float (&hf)[8])
{
    f32x4 acc[8];
    // round 0: state hi x hi (C = bias)
    acc[0] = MFMA(WhH[0], Hh, brz[0]);
    acc[1] = MFMA(WhH[1], Hh, brz[1]);
    acc[2] = MFMA(WhH[2], Hh, brz[2]);
    acc[3] = MFMA(WhH[3], Hh, brz[3]);
    acc[6] = MFMA(WhH[4], Hh, bhn[0]);
    acc[7] = MFMA(WhH[5], Hh, bhn[1]);
    FENCE();
    // round 1: state hi x lo
    acc[0] = MFMA(WhH[0], Hl, acc[0]);
    acc[1] = MFMA(WhH[1], Hl, acc[1]);
    acc[2] = MFMA(WhH[2], Hl, acc[2]);
    acc[3] = MFMA(WhH[3], Hl, acc[3]);
    acc[6] = MFMA(WhH[4], Hl, acc[6]);
    acc[7] = MFMA(WhH[5], Hl, acc[7]);
    FENCE();
    // round 2: state lo x hi
    acc[0] = MFMA(WhL[0], Hh, acc[0]);
    acc[1] = MFMA(WhL[1], Hh, acc[1]);
    acc[2] = MFMA(WhL[2], Hh, acc[2]);
    acc[3] = MFMA(WhL[3], Hh, acc[3]);
    acc[6] = MFMA(WhL[4], Hh, acc[6]);
    acc[7] = MFMA(WhL[5], Hh, acc[7]);
    FENCE();
    // round 3: input hi x hi
    acc[0] = MFMA(WxH[0], inh, acc[0]);
    acc[1] = MFMA(WxH[1], inh, acc[1]);
    acc[2] = MFMA(WxH[2], inh, acc[2]);
    acc[3] = MFMA(WxH[3], inh, acc[3]);
    acc[4] = MFMA(WxH[4], inh, bxn[0]);
    acc[5] = MFMA(WxH[5], inh, bxn[1]);
    FENCE();
    // round 4: input hi x lo
    acc[0] = MFMA(WxH[0], inl, acc[0]);
    acc[1] = MFMA(WxH[1], inl, acc[1]);
    acc[2] = MFMA(WxH[2], inl, acc[2]);
    acc[3] = MFMA(WxH[3], inl, acc[3]);
    acc[4] = MFMA(WxH[4], inl, acc[4]);
    acc[5] = MFMA(WxH[5], inl, acc[5]);
    FENCE();
    // round 5: input lo x hi
    acc[0] = MFMA(WxL[0], inh, acc[0]);
    acc[1] = MFMA(WxL[1], inh, acc[1]);
    acc[2] = MFMA(WxL[2], inh, acc[2]);
    acc[3] = MFMA(WxL[3], inh, acc[3]);
    acc[4] = MFMA(WxL[4], inh, acc[4]);
    acc[5] = MFMA(WxL[5], inh, acc[5]);
    FENCE();

    // gates: 8 independent element chains, level-major
    float vr[8], vz[8], vax[8], vah[8];
    #pragma unroll
    for (int e = 0; e < 8; ++e) {
        const int s = e >> 2, j = e & 3;
        vr[e]  = acc[s][j];
        vz[e]  = acc[2 + s][j];
        vax[e] = acc[4 + s][j];
        vah[e] = acc[6 + s][j];
    }
    float er[8], ez[8];
    #pragma unroll
    for (int e = 0; e < 8; ++e) er[e] = __builtin_amdgcn_exp2f(vr[e] * NL2E);
    #pragma unroll
    for (int e = 0; e < 8; ++e) ez[e] = __builtin_amdgcn_exp2f(vz[e] * NL2E);
    FENCE();
    float gr[8], gz[8];
    #pragma unroll
    for (int e = 0; e < 8; ++e) gr[e] = __builtin_amdgcn_rcpf(1.f + er[e]);
    #pragma unroll
    for (int e = 0; e < 8; ++e) gz[e] = __builtin_amdgcn_rcpf(1.f + ez[e]);
    FENCE();
    float en[8];
    #pragma unroll
    for (int e = 0; e < 8; ++e) {
        float u = fmaf(gr[e], vah[e], vax[e]);
        en[e] = __builtin_amdgcn_exp2f(fminf(u * N2L2E, 126.f));
    }
    FENCE();
    float qn[8];
    #pragma unroll
    for (int e = 0; e < 8; ++e) qn[e] = __builtin_amdgcn_rcpf(1.f + en[e]);
    FENCE();
    #pragma unroll
    for (int e = 0; e < 8; ++e) {
        float nn = fmaf(en[e] * qn[e], -2.f, 1.f);
        hf[e] = fmaf(gz[e], hf[e] - nn, nn);
    }
    pack_frag_tr(hf, Hh, Hl);
}

// Block = 128 threads = 2 waves, 16 batches. Wave 0 runs layer 0 (input x[t]),
// wave 1 runs layer 1 (input h0[t-1] via LDS, 1-step stagger). Each wave's
// footprint (~240 VGPR) fits the 256 arch cap -> true register residency.
// Frag map per lane: batch = b0+(lane&15), q = lane>>4; elements 0..3 = units
// 4q+j, 4..7 = 16+4q+j (same map for A and B). D: col=lane&15, row=4q+reg.
__global__ __launch_bounds__(128, 1)
void gru2_split(const float* __restrict__ x,
                const float* __restrict__ W_ih0, const float* __restrict__ W_hh0,
                const float* __restrict__ b_ih0, const float* __restrict__ b_hh0,
                const float* __restrict__ W_ih1, const float* __restrict__ W_hh1,
                const float* __restrict__ b_ih1, const float* __restrict__ b_hh1,
                const float* __restrict__ W_proj, const float* __restrict__ b_proj,
                float* __restrict__ out)
{
    const int tid  = threadIdx.x;
    const int wid  = tid >> 6;
    const int lane = tid & 63;
    const int r16  = lane & 15;
    const int q    = lane >> 4;
    const int b0   = blockIdx.x * 16;

    __shared__ u32x4 ldsHh[2][64];   // h0 frags, double-buffered (2 KB)
    __shared__ u32x4 ldsHl[2][64];   // 2 KB

    // ---- this wave's layer weights (hi/lo split), register-resident ----
    const float* WxP = wid ? W_ih1 : W_ih0;
    const float* WhP = wid ? W_hh1 : W_hh0;
    const float* bxP = wid ? b_ih1 : b_ih0;
    const float* bhP = wid ? b_hh1 : b_hh0;

    bf16x8 WxH[6], WxL[6], WhH[6], WhL[6];
    #pragma unroll
    for (int t = 0; t < 6; ++t) {
        const float* p1 = WxP + (16 * t + r16) * 32 + 4 * q;
        split8_tr(*(const f32x4*)p1, *(const f32x4*)(p1 + 16), WxH[t], WxL[t]);
        const float* p2 = WhP + (16 * t + r16) * 32 + 4 * q;
        split8_tr(*(const f32x4*)p2, *(const f32x4*)(p2 + 16), WhH[t], WhL[t]);
    }
    f32x4 brz[4], bxn[2], bhn[2];
    #pragma unroll
    for (int t = 0; t < 4; ++t)
        brz[t] = *(const f32x4*)(bxP + 16 * t + 4 * q) + *(const f32x4*)(bhP + 16 * t + 4 * q);
    #pragma unroll
    for (int s = 0; s < 2; ++s) {
        bxn[s] = *(const f32x4*)(bxP + 64 + 16 * s + 4 * q);
        bhn[s] = *(const f32x4*)(bhP + 64 + 16 * s + 4 * q);
    }

    // ---- state ----
    bf16x8 Hh = {}, Hl = {};
    float hf[8] = {};

    const float* xp = x + (size_t)(b0 + r16) * (T_SEQ * 32) + 4 * q;
    f32x4 xA = {}, xB = {};
    if (wid == 0) {
        xA = *(const f32x4*)(xp);
        xB = *(const f32x4*)(xp + 16);
    }

    // ---- prologue: wave 0 computes h0[0] (state = 0), publishes to buf 0 ----
    if (wid == 0) {
        bf16x8 xh, xl;
        split8_tr(xA, xB, xh, xl);
        xA = *(const f32x4*)(xp + 32);       // prefetch x[1]
        xB = *(const f32x4*)(xp + 48);
        wave_step(WxH, WxL, WhH, WhL, brz, bxn, bhn, xh, xl, Hh, Hl, hf);
        ldsHh[0][lane] = __builtin_bit_cast(u32x4, Hh);
        ldsHl[0][lane] = __builtin_bit_cast(u32x4, Hl);
    }

    // ---- main loop: wave 0 -> h0[t], wave 1 -> h1[t-1] ----
    #pragma unroll 1
    for (int t = 1; t < T_SEQ; ++t) {
        __syncthreads();                     // h0[t-1] publication visible
        bf16x8 inh, inl;
        if (wid == 0) {
            split8_tr(xA, xB, inh, inl);     // x[t]
            const float* nx = xp + (size_t)((t + 1 < T_SEQ) ? t + 1 : t) * 32;
            xA = *(const f32x4*)(nx);        // prefetch x[t+1]
            xB = *(const f32x4*)(nx + 16);
        } else {
            inh = __builtin_bit_cast(bf16x8, ldsHh[(t - 1) & 1][lane]);
            inl = __builtin_bit_cast(bf16x8, ldsHl[(t - 1) & 1][lane]);
        }
        wave_step(WxH, WxL, WhH, WhL, brz, bxn, bhn, inh, inl, Hh, Hl, hf);
        if (wid == 0) {
            ldsHh[t & 1][lane] = __builtin_bit_cast(u32x4, Hh);
            ldsHl[t & 1][lane] = __builtin_bit_cast(u32x4, Hl);
        }
    }

    __syncthreads();                         // h0[511] (buf 1) visible
    if (wid == 1) {
        // final step: h1[511] from h0[511] and h1[510]
        bf16x8 inh = __builtin_bit_cast(bf16x8, ldsHh[1][lane]);
        bf16x8 inl = __builtin_bit_cast(bf16x8, ldsHl[1][lane]);
        wave_step(WxH, WxL, WhH, WhL, brz, bxn, bhn, inh, inl, Hh, Hl, hf);

        // projection: out[b][o] = b_proj[o] + sum_u W_proj[o][u] * h1[u]
        const float* pp = W_proj + r16 * 32 + 4 * q;
        bf16x8 Wph, Wpl;
        split8_tr(*(const f32x4*)pp, *(const f32x4*)(pp + 16), Wph, Wpl);
        f32x4 accp = *(const f32x4*)(b_proj + 4 * q);   // element reg -> output 4q+reg
        accp = MFMA(Wph, Hh, accp);
        accp = MFMA(Wph, Hl, accp);
        accp = MFMA(Wpl, Hh, accp);
        #pragma unroll
        for (int rg = 0; rg < 4; ++rg)
            out[(b0 + r16) * 16 + 4 * q + rg] = accp[rg];
    }
}

extern "C" void kernel_launch(void* const* d_in, const int* in_sizes, int n_in,
                              void* d_out, int out_size, void* d_ws, size_t ws_size,
                              hipStream_t stream) {
    const float* x      = (const float*)d_in[0];
    const float* W_ih0  = (const float*)d_in[1];
    const float* W_hh0  = (const float*)d_in[2];
    const float* b_ih0  = (const float*)d_in[3];
    const float* b_hh0  = (const float*)d_in[4];
    const float* W_ih1  = (const float*)d_in[5];
    const float* W_hh1  = (const float*)d_in[6];
    const float* b_ih1  = (const float*)d_in[7];
    const float* b_hh1  = (const float*)d_in[8];
    const float* W_proj = (const float*)d_in[9];
    const float* b_proj = (const float*)d_in[10];
    float* out = (float*)d_out;

    const int nb   = in_sizes[0] / (T_SEQ * 32);   // 4096 batch elements
    const int grid = nb / 16;                      // 16 batches per 2-wave block

    hipLaunchKernelGGL(gru2_split, dim3(grid), dim3(128), 0, stream,
                       x, W_ih0, W_hh0, b_ih0, b_hh0,
                       W_ih1, W_hh1, b_ih1, b_hh1, W_proj, b_proj, out);
}

// Round 9
// 291.952 us; speedup vs baseline: 3.2529x; 1.4547x over previous
//
#include <hip/hip_runtime.h>

using bf16x8 = __attribute__((ext_vector_type(8))) short;
using short8 = __attribute__((ext_vector_type(8))) short;
using s16x4  = __attribute__((ext_vector_type(4))) short;
using f32x4  = __attribute__((ext_vector_type(4))) float;
using u32x4  = __attribute__((ext_vector_type(4))) unsigned;
using ull    = unsigned long long;

#define T_SEQ 512
#define MFMA(A, B, C) __builtin_amdgcn_mfma_f32_16x16x32_bf16((A), (B), (C), 0, 0, 0)

static constexpr float NL2E  = -1.44269504f;   // -log2(e)
static constexpr float N2L2E = -2.88539008f;   // -2*log2(e)

// Truncation split: hi = bf16-truncate(v), lo = bf16-truncate(v - hi) (residual exact).
__device__ __forceinline__ void split8_tr(f32x4 a, f32x4 b, bf16x8& hi, bf16x8& lo) {
    u32x4 ua = __builtin_bit_cast(u32x4, a);
    u32x4 ub = __builtin_bit_cast(u32x4, b);
    u32x4 m  = {0xffff0000u, 0xffff0000u, 0xffff0000u, 0xffff0000u};
    f32x4 ra = a - __builtin_bit_cast(f32x4, ua & m);
    f32x4 rb = b - __builtin_bit_cast(f32x4, ub & m);
    short8 sa  = __builtin_bit_cast(short8, a);
    short8 sb  = __builtin_bit_cast(short8, b);
    short8 sra = __builtin_bit_cast(short8, ra);
    short8 srb = __builtin_bit_cast(short8, rb);
    hi = __builtin_shufflevector(sa, sb, 1, 3, 5, 7, 9, 11, 13, 15);
    lo = __builtin_shufflevector(sra, srb, 1, 3, 5, 7, 9, 11, 13, 15);
}

__device__ __forceinline__ void split4_tr(f32x4 a, s16x4& hi, s16x4& lo) {
    u32x4 ua = __builtin_bit_cast(u32x4, a);
    u32x4 m  = {0xffff0000u, 0xffff0000u, 0xffff0000u, 0xffff0000u};
    f32x4 ra = a - __builtin_bit_cast(f32x4, ua & m);
    short8 sa  = __builtin_bit_cast(short8, a);
    short8 sra = __builtin_bit_cast(short8, ra);
    hi = __builtin_shufflevector(sa, sa, 1, 3, 5, 7);
    lo = __builtin_shufflevector(sra, sra, 1, 3, 5, 7);
}

// Gates for this wave's 4 hidden units. aR/aZ are state+input merged pre-acts;
// n-gate keeps input side (iN) and state side (sN) separate. Level-major 4-wide.
__device__ __forceinline__ void gate4(f32x4 aR, f32x4 aZ, f32x4 iN, f32x4 sN,
                                      float (&hf)[4]) {
    float er[4], ez[4];
    #pragma unroll
    for (int j = 0; j < 4; ++j) er[j] = __builtin_amdgcn_exp2f(aR[j] * NL2E);
    #pragma unroll
    for (int j = 0; j < 4; ++j) ez[j] = __builtin_amdgcn_exp2f(aZ[j] * NL2E);
    float gr[4], gz[4];
    #pragma unroll
    for (int j = 0; j < 4; ++j) gr[j] = __builtin_amdgcn_rcpf(1.f + er[j]);
    #pragma unroll
    for (int j = 0; j < 4; ++j) gz[j] = __builtin_amdgcn_rcpf(1.f + ez[j]);
    float en[4];
    #pragma unroll
    for (int j = 0; j < 4; ++j) {
        float u = fmaf(gr[j], sN[j], iN[j]);
        en[j] = __builtin_amdgcn_exp2f(fminf(u * N2L2E, 126.f));
    }
    float qn[4];
    #pragma unroll
    for (int j = 0; j < 4; ++j) qn[j] = __builtin_amdgcn_rcpf(1.f + en[j]);
    #pragma unroll
    for (int j = 0; j < 4; ++j) {
        float nn = fmaf(en[j] * qn[j], -2.f, 1.f);
        hf[j] = fmaf(gz[j], hf[j] - nn, nn);
    }
}

// Block = 256 threads = 4 waves = (layer L, row-half m). Wave (L,m) owns tiles
// {m, 2+m, 4+m} (r,z,n for hidden units 16m+4q+j) and publishes its 4 h/lane to
// LDS; half0's outputs are frag elements 0..3, half1's are 4..7 at the SAME
// lane, so a full state B-frag is one contiguous 16B ds_read per lane.
// Frag map: batch = b0+(lane&15), q = lane>>4; elems 0..3 = units 4q+j,
// 4..7 = 16+4q+j (same map A and B). D: col=lane&15, row=4q+reg (m89).
__global__ __launch_bounds__(256, 1)
void gru2_quad(const float* __restrict__ x,
               const float* __restrict__ W_ih0, const float* __restrict__ W_hh0,
               const float* __restrict__ b_ih0, const float* __restrict__ b_hh0,
               const float* __restrict__ W_ih1, const float* __restrict__ W_hh1,
               const float* __restrict__ b_ih1, const float* __restrict__ b_hh1,
               const float* __restrict__ W_proj, const float* __restrict__ b_proj,
               float* __restrict__ out)
{
    const int tid  = threadIdx.x;
    const int wid  = tid >> 6;
    const int L    = wid >> 1;        // 0: layer0, 1: layer1
    const int m    = wid & 1;         // row half
    const int lane = tid & 63;
    const int r16  = lane & 15;
    const int q    = lane >> 4;
    const int b0   = blockIdx.x * 16;

    // publications: [layer][parity][lane][half], hi and lo bf16 halves (8 KB)
    __shared__ ull pubH[2][2][64][2];
    __shared__ ull pubL[2][2][64][2];

    const float* Wx = L ? W_ih1 : W_ih0;
    const float* Wh = L ? W_hh1 : W_hh0;
    const float* bx = L ? b_ih1 : b_ih0;
    const float* bh = L ? b_hh1 : b_hh0;

    // weight fragments for tiles {m, 2+m, 4+m}; g: 0=r, 1=z, 2=n
    bf16x8 WxH[3], WxL[3], WhH[3], WhL[3];
    f32x4 bxf[3], bhf[3];
    #pragma unroll
    for (int g = 0; g < 3; ++g) {
        const int tile = 2 * g + m;
        const float* p1 = Wx + (16 * tile + r16) * 32 + 4 * q;
        split8_tr(*(const f32x4*)p1, *(const f32x4*)(p1 + 16), WxH[g], WxL[g]);
        const float* p2 = Wh + (16 * tile + r16) * 32 + 4 * q;
        split8_tr(*(const f32x4*)p2, *(const f32x4*)(p2 + 16), WhH[g], WhL[g]);
        bxf[g] = *(const f32x4*)(bx + 16 * tile + 4 * q);
        bhf[g] = *(const f32x4*)(bh + 16 * tile + 4 * q);
    }

    float hf[4] = {0.f, 0.f, 0.f, 0.f};
    bf16x8 inh = {}, inl = {};
    const float* xp = x + (size_t)(b0 + r16) * (T_SEQ * 32) + 4 * q;
    f32x4 xA = {}, xB = {};

    if (L == 0) {
        xA = *(const f32x4*)(xp);
        xB = *(const f32x4*)(xp + 16);
        // prologue: h0[0] from x[0], state = 0 (state accs = b_hh frags)
        split8_tr(xA, xB, inh, inl);
        xA = *(const f32x4*)(xp + 32);       // prefetch x[1]
        xB = *(const f32x4*)(xp + 48);
        f32x4 iR = MFMA(WxH[0], inh, bxf[0]);
        f32x4 iZ = MFMA(WxH[1], inh, bxf[1]);
        f32x4 iN = MFMA(WxH[2], inh, bxf[2]);
        iR = MFMA(WxH[0], inl, iR); iZ = MFMA(WxH[1], inl, iZ); iN = MFMA(WxH[2], inl, iN);
        iR = MFMA(WxL[0], inh, iR); iZ = MFMA(WxL[1], inh, iZ); iN = MFMA(WxL[2], inh, iN);
        gate4(iR + bhf[0], iZ + bhf[1], iN, bhf[2], hf);
        s16x4 hi4, lo4;
        split4_tr(f32x4{hf[0], hf[1], hf[2], hf[3]}, hi4, lo4);
        pubH[0][0][lane][m] = __builtin_bit_cast(ull, hi4);
        pubL[0][0][lane][m] = __builtin_bit_cast(ull, lo4);
    } else {
        // zero h1's initial state buffer (read at t=1 as pub1[1])
        if (m == 0) { pubH[1][1][lane][0] = 0; pubH[1][1][lane][1] = 0; }
        else        { pubL[1][1][lane][0] = 0; pubL[1][1][lane][1] = 0; }
    }

    // ---- main loop: wave (0,m) -> h0[t] half, wave (1,m) -> h1[t-1] half ----
    #pragma unroll 1
    for (int t = 1; t < T_SEQ; ++t) {
        __syncthreads();                 // iter t-1 publications visible
        const int pPrev = (t - 1) & 1;
        const int pCur  = t & 1;
        bf16x8 Sh, Sl;
        if (L == 0) {
            Sh = __builtin_bit_cast(bf16x8, *(const u32x4*)&pubH[0][pPrev][lane][0]);
            Sl = __builtin_bit_cast(bf16x8, *(const u32x4*)&pubL[0][pPrev][lane][0]);
            split8_tr(xA, xB, inh, inl); // x[t] (register) under the ds_read wait
            const float* nx = xp + (size_t)((t + 1 < T_SEQ) ? t + 1 : t) * 32;
            xA = *(const f32x4*)(nx);    // prefetch x[t+1]
            xB = *(const f32x4*)(nx + 16);
        } else {
            inh = __builtin_bit_cast(bf16x8, *(const u32x4*)&pubH[0][pPrev][lane][0]);
            inl = __builtin_bit_cast(bf16x8, *(const u32x4*)&pubL[0][pPrev][lane][0]);
            Sh  = __builtin_bit_cast(bf16x8, *(const u32x4*)&pubH[1][pCur][lane][0]);
            Sl  = __builtin_bit_cast(bf16x8, *(const u32x4*)&pubL[1][pCur][lane][0]);
        }

        // 18 MFMAs: input-side chains first (L0: register inputs cover the
        // state ds_read latency), then state-side chains. 6 independent accs.
        f32x4 iR = MFMA(WxH[0], inh, bxf[0]);
        f32x4 iZ = MFMA(WxH[1], inh, bxf[1]);
        f32x4 iN = MFMA(WxH[2], inh, bxf[2]);
        iR = MFMA(WxH[0], inl, iR); iZ = MFMA(WxH[1], inl, iZ); iN = MFMA(WxH[2], inl, iN);
        iR = MFMA(WxL[0], inh, iR); iZ = MFMA(WxL[1], inh, iZ); iN = MFMA(WxL[2], inh, iN);
        f32x4 sR = MFMA(WhH[0], Sh, bhf[0]);
        f32x4 sZ = MFMA(WhH[1], Sh, bhf[1]);
        f32x4 sN = MFMA(WhH[2], Sh, bhf[2]);
        sR = MFMA(WhH[0], Sl, sR); sZ = MFMA(WhH[1], Sl, sZ); sN = MFMA(WhH[2], Sl, sN);
        sR = MFMA(WhL[0], Sh, sR); sZ = MFMA(WhL[1], Sh, sZ); sN = MFMA(WhL[2], Sh, sN);

        gate4(sR + iR, sZ + iZ, iN, sN, hf);

        s16x4 hi4, lo4;
        split4_tr(f32x4{hf[0], hf[1], hf[2], hf[3]}, hi4, lo4);
        const int pW = (L == 0) ? pCur : pPrev;   // L0 writes h0[t], L1 writes h1[t-1]
        pubH[L][pW][lane][m] = __builtin_bit_cast(ull, hi4);
        pubL[L][pW][lane][m] = __builtin_bit_cast(ull, lo4);
    }

    __syncthreads();                     // h0[511] (pub0[1]), h1[510] (pub1[0]) visible
    if (L == 1) {
        // final step: h1[511] from h0[511] and h1[510]
        bf16x8 i2h = __builtin_bit_cast(bf16x8, *(const u32x4*)&pubH[0][1][lane][0]);
        bf16x8 i2l = __builtin_bit_cast(bf16x8, *(const u32x4*)&pubL[0][1][lane][0]);
        bf16x8 Sh  = __builtin_bit_cast(bf16x8, *(const u32x4*)&pubH[1][0][lane][0]);
        bf16x8 Sl  = __builtin_bit_cast(bf16x8, *(const u32x4*)&pubL[1][0][lane][0]);
        f32x4 iR = MFMA(WxH[0], i2h, bxf[0]);
        f32x4 iZ = MFMA(WxH[1], i2h, bxf[1]);
        f32x4 iN = MFMA(WxH[2], i2h, bxf[2]);
        iR = MFMA(WxH[0], i2l, iR); iZ = MFMA(WxH[1], i2l, iZ); iN = MFMA(WxH[2], i2l, iN);
        iR = MFMA(WxL[0], i2h, iR); iZ = MFMA(WxL[1], i2h, iZ); iN = MFMA(WxL[2], i2h, iN);
        f32x4 sR = MFMA(WhH[0], Sh, bhf[0]);
        f32x4 sZ = MFMA(WhH[1], Sh, bhf[1]);
        f32x4 sN = MFMA(WhH[2], Sh, bhf[2]);
        sR = MFMA(WhH[0], Sl, sR); sZ = MFMA(WhH[1], Sl, sZ); sN = MFMA(WhH[2], Sl, sN);
        sR = MFMA(WhL[0], Sh, sR); sZ = MFMA(WhL[1], Sh, sZ); sN = MFMA(WhL[2], Sh, sN);
        gate4(sR + iR, sZ + iZ, iN, sN, hf);
        s16x4 hi4, lo4;
        split4_tr(f32x4{hf[0], hf[1], hf[2], hf[3]}, hi4, lo4);
        pubH[1][1][lane][m] = __builtin_bit_cast(ull, hi4);   // h1[511]
        pubL[1][1][lane][m] = __builtin_bit_cast(ull, lo4);
    }
    __syncthreads();

    if (wid == 2) {
        // projection: out[b][o] = b_proj[o] + sum_u W_proj[o][u] * h1[u]
        bf16x8 Hh = __builtin_bit_cast(bf16x8, *(const u32x4*)&pubH[1][1][lane][0]);
        bf16x8 Hl = __builtin_bit_cast(bf16x8, *(const u32x4*)&pubL[1][1][lane][0]);
        const float* pp = W_proj + r16 * 32 + 4 * q;
        bf16x8 Wph, Wpl;
        split8_tr(*(const f32x4*)pp, *(const f32x4*)(pp + 16), Wph, Wpl);
        f32x4 accp = *(const f32x4*)(b_proj + 4 * q);   // elem reg -> output 4q+reg
        accp = MFMA(Wph, Hh, accp);
        accp = MFMA(Wph, Hl, accp);
        accp = MFMA(Wpl, Hh, accp);
        #pragma unroll
        for (int rg = 0; rg < 4; ++rg)
            out[(b0 + r16) * 16 + 4 * q + rg] = accp[rg];
    }
}

extern "C" void kernel_launch(void* const* d_in, const int* in_sizes, int n_in,
                              void* d_out, int out_size, void* d_ws, size_t ws_size,
                              hipStream_t stream) {
    const float* x      = (const float*)d_in[0];
    const float* W_ih0  = (const float*)d_in[1];
    const float* W_hh0  = (const float*)d_in[2];
    const float* b_ih0  = (const float*)d_in[3];
    const float* b_hh0  = (const float*)d_in[4];
    const float* W_ih1  = (const float*)d_in[5];
    const float* W_hh1  = (const float*)d_in[6];
    const float* b_ih1  = (const float*)d_in[7];
    const float* b_hh1  = (const float*)d_in[8];
    const float* W_proj = (const float*)d_in[9];
    const float* b_proj = (const float*)d_in[10];
    float* out = (float*)d_out;

    const int nb   = in_sizes[0] / (T_SEQ * 32);   // 4096 batch elements
    const int grid = nb / 16;                      // 16 batches per 4-wave block

    hipLaunchKernelGGL(gru2_quad, dim3(grid), dim3(256), 0, stream,
                       x, W_ih0, W_hh0, b_ih0, b_hh0,
                       W_ih1, W_hh1, b_ih1, b_hh1, W_proj, b_proj, out);
}